// Round 13
// baseline (71.362 us; speedup 1.0000x reference)
//
#include <hip/hip_runtime.h>

// Problem constants (match reference)
#define XD 256
#define YD 256
#define ZD 16
#define TD 5
#define BD 2
#define NP 300000
#define CMID 8
#define VPB (XD * YD * ZD * TD)        // 5,242,880 voxels per batch
#define NVOX (BD * VPB)                // 10,485,760 total voxels
#define MAXPTS (BD * NP)               // 600,000
// Bit-packed occupancy: 8 bits per (b,x,y,z) cell (t in bits 0..4).
// idx8 = (b<<23)|(x<<15)|(y<<7)|(z<<3)|t. Column (b,x,y) = 16 B (z 0..15).
#define OCC_BYTES (BD * XD * YD * ZD)  // 2 MiB (L2-resident)
#define OCC_U128  (OCC_BYTES / 16)     // 131,072 columns

#define SCAT_BLOCKS ((MAXPTS + 255) / 256)   // 2344
#define CONV_BLOCKS 2048                     // one (b, x, y-quarter) strip each
#define STRIP 5120                           // 64 cols * 80 outputs per strip

// ---------------------------------------------------------------------------
// Kernel 0: zero the 2 MiB occupancy bitfield.
// ---------------------------------------------------------------------------
__global__ __launch_bounds__(256) void zero_occ_kernel(uint4* __restrict__ occ) {
    occ[blockIdx.x * 256 + threadIdx.x] = uint4{0u, 0u, 0u, 0u};
}

// ---------------------------------------------------------------------------
// Kernel 1: scatter points -> occupancy bits (idempotent atomicOr).
// ---------------------------------------------------------------------------
__global__ __launch_bounds__(256) void scatter_kernel(
    const float4* __restrict__ pts, unsigned int* __restrict__ occ) {
    int i = blockIdx.x * 256 + threadIdx.x;
    if (i >= MAXPTS) return;
    float4 p = pts[i];
    // Match JAX exactly: floor(p / quant) (fp32 division), then clip.
    int cx = min(max((int)floorf(p.x / 0.4f), 0), XD - 1);
    int cy = min(max((int)floorf(p.y / 0.4f), 0), YD - 1);
    int cz = min(max((int)floorf(p.z / 0.4f), 0), ZD - 1);
    int ct = min(max((int)floorf(p.w / 1.0f), 0), TD - 1);
    int b  = i / NP;
    unsigned idx8 = ((unsigned)b << 23) | ((unsigned)cx << 15) |
                    ((unsigned)cy << 7) | ((unsigned)cz << 3) | (unsigned)ct;
    atomicOr(&occ[idx8 >> 5], 1u << (idx8 & 31));
}

// ---------------------------------------------------------------------------
// Kernel 2: column-register conv. Block owns strip (b, x, ny0..ny0+63) and is
// sole writer of its 20 KB output. Thread = (column cl = tid>>2, z-quarter
// zq = tid&3):
//   1. 9 neighbor columns -> registers. COALESCED: adjacent lanes own
//      adjacent y -> each load is a 256B-contiguous 4-lane-broadcast hit on
//      the L2-resident 2 MB bitfield. No LDS staging, no queue, no
//      divergent addresses.
//   2. iterate set bits of own u32 word (avg ~1.1): 27-tap m-table conv
//      from registers, ~4.3 predicated tab (LDS) reads, ReLU + 8->1 proj,
//      scatter into LDS out-tile.
//   3. dense coalesced float4 store of the whole strip (no zero pass, no
//      write-allocate refetch).
// ---------------------------------------------------------------------------
__global__ __launch_bounds__(256) void conv_kernel(
    const ulonglong2* __restrict__ occ128,
    const float* __restrict__ W0,   // (81, 1, 8)
    const float* __restrict__ b0,   // (8)
    const float* __restrict__ W1,   // (8, 1)
    const float* __restrict__ b1,   // (1)
    float4* __restrict__ out4) {
    __shared__ float tab[216 * 12];   // 10.4 KB mask table
    __shared__ float outt[STRIP];     // 20.5 KB dense out-tile
    __shared__ float b0s[CMID];
    __shared__ float w1s[CMID];
    __shared__ float b1s;

    int tid = threadIdx.x;
    int s   = blockIdx.x;
    int b   = s >> 10;
    int x   = (s >> 2) & 255;
    int ny0 = (s & 3) << 6;

    // --- zero out-tile (5 float4 per thread) ---
    float4* ot4 = (float4*)outt;
    float4 zf = {0.f, 0.f, 0.f, 0.f};
#pragma unroll
    for (int j = 0; j < 5; ++j) ot4[tid + j * 256] = zf;

    // --- mask table: entry e = kb[0,27)*8 + m[0,8); rows padded to 12 ---
    if (tid < 216) {
        int kb = tid >> 3;
        int m  = tid & 7;
        float acc[CMID];
#pragma unroll
        for (int c = 0; c < CMID; ++c) acc[c] = 0.0f;
#pragma unroll
        for (int dti = 0; dti < 3; ++dti) {
            if ((m >> dti) & 1) {
                const float* w = &W0[(kb * 3 + dti) * CMID];
#pragma unroll
                for (int c = 0; c < CMID; ++c) acc[c] += w[c];
            }
        }
#pragma unroll
        for (int c = 0; c < CMID; ++c) tab[tid * 12 + c] = acc[c];
    }
    if (tid < CMID) {
        b0s[tid] = b0[tid];
        w1s[tid] = W1[tid];
    }
    if (tid == 0) b1s = b1[0];

    // --- 9 neighbor columns into registers (coalesced, 4-lane broadcast) ---
    int cl = tid >> 2;
    int zq = tid & 3;
    ulonglong2 cr[3][3];
#pragma unroll
    for (int dxi = 0; dxi < 3; ++dxi) {
        int nx = x + dxi - 1;
#pragma unroll
        for (int dyi = 0; dyi < 3; ++dyi) {
            int cy = ny0 + cl + dyi - 1;
            bool valid = ((unsigned)nx < XD) && ((unsigned)cy < YD);
            ulonglong2 col = occ128[(b << 16) | ((nx & 255) << 8) | (cy & 255)];
            cr[dxi][dyi].x = valid ? col.x : 0ull;
            cr[dxi][dyi].y = valid ? col.y : 0ull;
        }
    }

    __syncthreads();   // tab/outt/b0s ready before bit-loop reads them

    // --- own u32 word: z in [zq*4, zq*4+4), bit layout (z<<3)|t ---
    unsigned long long hw = (zq & 2) ? cr[1][1].y : cr[1][1].x;
    unsigned w = (unsigned)((zq & 1) ? (hw >> 32) : hw);

    while (w) {
        int bi = __ffs(w) - 1;
        w &= w - 1;
        int z = (zq << 2) + (bi >> 3);
        int t = bi & 7;

        float4 h0 = {0.f, 0.f, 0.f, 0.f};
        float4 h1 = {0.f, 0.f, 0.f, 0.f};
#pragma unroll
        for (int dxi = 0; dxi < 3; ++dxi) {
#pragma unroll
            for (int dyi = 0; dyi < 3; ++dyi) {
                ulonglong2 col = cr[dxi][dyi];      // registers
                int p3 = (dxi * 3 + dyi) * 3;
#pragma unroll
                for (int dzi = 0; dzi < 3; ++dzi) {
                    int nz = z + dzi - 1;                     // [-1, 16]
                    unsigned sh = ((unsigned)nz * 8u) & 63u;  // wrap-safe
                    unsigned r = (unsigned)(((nz & 8) ? (col.y >> sh)
                                                      : (col.x >> sh)) & 0xffull);
                    r = ((unsigned)nz < ZD) ? r : 0u;
                    unsigned m = ((r << 1) >> t) & 7u;  // bits t-1,t,t+1
                    if (m) {                            // ~16% of taps fire
                        const float4* row =
                            (const float4*)&tab[((p3 + dzi) * 8 + (int)m) * 12];
                        h0 += row[0];
                        h1 += row[1];
                    }
                }
            }
        }

        float hc[CMID] = {h0.x, h0.y, h0.z, h0.w, h1.x, h1.y, h1.z, h1.w};
        float o = 0.0f;
#pragma unroll
        for (int c = 0; c < CMID; ++c) {
            float v = 0.5f * hc[c] + b0s[c];   // grid value is exactly 0.5
            v = v > 0.0f ? v : 0.0f;           // relu
            o += v * w1s[c];
        }
        outt[cl * 80 + z * 5 + t] = o + b1s;
    }
    __syncthreads();

    // --- dense coalesced store of the whole strip (sole writer) ---
    const float4* src = (const float4*)outt;
    float4* dst = out4 + ((size_t)b * (VPB / 4)) + (size_t)(x * YD + ny0) * 20;
#pragma unroll
    for (int j = 0; j < 5; ++j) dst[tid + j * 256] = src[tid + j * 256];
}

extern "C" void kernel_launch(void* const* d_in, const int* in_sizes, int n_in,
                              void* d_out, int out_size, void* d_ws, size_t ws_size,
                              hipStream_t stream) {
    const float4* pts = (const float4*)d_in[0];
    const float* W0   = (const float*)d_in[1];
    const float* b0   = (const float*)d_in[2];
    const float* W1   = (const float*)d_in[3];
    const float* b1   = (const float*)d_in[4];
    unsigned int* occ = (unsigned int*)d_ws;   // 2 MiB bitfield

    zero_occ_kernel<<<OCC_U128 / 256, 256, 0, stream>>>((uint4*)occ);
    scatter_kernel<<<SCAT_BLOCKS, 256, 0, stream>>>(pts, occ);
    conv_kernel<<<CONV_BLOCKS, 256, 0, stream>>>(
        (const ulonglong2*)occ, W0, b0, W1, b1, (float4*)d_out);
}

// Round 14
// 52.898 us; speedup vs baseline: 1.3490x; 1.3490x over previous
//
#include <hip/hip_runtime.h>

// Problem constants (match reference)
#define XD 256
#define YD 256
#define ZD 16
#define TD 5
#define BD 2
#define NP 300000
#define CMID 8
#define VPB (XD * YD * ZD * TD)        // 5,242,880 voxels per batch
#define NVOX (BD * VPB)                // 10,485,760 total voxels
#define MAXPTS (BD * NP)               // 600,000

// Byte-per-voxel occupancy grid, t padded 5->8:
//   occ8[(colidx << 7) | (z << 3) | t], colidx = (b<<16)|(x<<8)|y
// Scatter = plain byte stores of 1 (no atomics; duplicate writes identical).
#define OCC8_BYTES (BD * XD * YD * ZD * 8)   // 16 MiB
#define OCC8_U128  (OCC8_BYTES / 16)         // 1,048,576

#define SCAT_BLOCKS ((MAXPTS + 255) / 256)   // 2344
#define CONV_BLOCKS 2048                     // one (b, x, y-quarter) strip each
#define STRIP 5120                           // 64 cols * 80 outputs per strip
#define QCAP 1024                            // strip occupancy ~283+-17; 43 sigma

// ---------------------------------------------------------------------------
// Kernel 0: zero the 16 MiB byte grid.
// ---------------------------------------------------------------------------
__global__ __launch_bounds__(256) void zero_kernel(uint4* __restrict__ occ) {
    int i = blockIdx.x * 256 + threadIdx.x;
    uint4 z = {0u, 0u, 0u, 0u};
    for (int j = i; j < OCC8_U128; j += 2048 * 256) occ[j] = z;
}

// ---------------------------------------------------------------------------
// Kernel 1: scatter points -> occupancy bytes (plain stores, NO atomics).
// Measured ~10 us in R11.
// ---------------------------------------------------------------------------
__global__ __launch_bounds__(256) void scatter_kernel(
    const float4* __restrict__ pts, unsigned char* __restrict__ occ8) {
    int i = blockIdx.x * 256 + threadIdx.x;
    if (i >= MAXPTS) return;
    float4 p = pts[i];
    // Match JAX exactly: floor(p / quant) (fp32 division), then clip.
    int cx = min(max((int)floorf(p.x / 0.4f), 0), XD - 1);
    int cy = min(max((int)floorf(p.y / 0.4f), 0), YD - 1);
    int cz = min(max((int)floorf(p.z / 0.4f), 0), ZD - 1);
    int ct = min(max((int)floorf(p.w / 1.0f), 0), TD - 1);
    int b  = i / NP;
    unsigned a = (((unsigned)b << 23) | ((unsigned)cx << 15) |
                  ((unsigned)cy << 7) | ((unsigned)cz << 3) | (unsigned)ct);
    occ8[a] = 1;
}

// LSB-gather: u64 of 8 bytes (each 0 or 1) -> 8-bit mask (byte j -> bit j).
__device__ __forceinline__ unsigned pack8(unsigned long long v) {
    v |= v >> 7;
    v |= v >> 14;
    v |= v >> 28;
    return (unsigned)v & 0xffu;
}

// ---------------------------------------------------------------------------
// Kernel 2: strip conv. Block owns columns (b, x, ny0..ny0+63), sole writer
// of its 20 KB output strip.
//   1. byte-grid neighborhood (3x66 cols) loaded coalesced + packed to bits
//      in registers -> 16 B/column in LDS (R11-verified staging)
//   2. shfl-scan compaction of own strip's occupied slots into an LDS queue
//      (load balance: ~1.1 entries/thread, wave-max ~2)  [R8-verified]
//   3. per entry: 27-tap m-table conv with THREE independent per-dxi partial
//      accumulators (ILP: tab reads pipeline instead of serializing on the
//      FP add chain), predicated on m!=0; ReLU + 8->1 proj -> LDS out-tile
//   4. dense coalesced float4 store of the strip (no zero pass needed)
// ---------------------------------------------------------------------------
__global__ __launch_bounds__(256) void conv_kernel(
    const ulonglong2* __restrict__ occ16,   // byte grid as 16B units
    const float* __restrict__ W0,   // (81, 1, 8)
    const float* __restrict__ b0,   // (8)
    const float* __restrict__ W1,   // (8, 1)
    const float* __restrict__ b1,   // (1)
    float4* __restrict__ out4) {
    __shared__ float tab[216 * 12];          // 10.4 KB mask table
    __shared__ ulonglong2 pcols[3 * 66];     // 3.2 KB packed columns
    __shared__ unsigned short queue[QCAP];   // 2 KB compacted entries
    __shared__ float outt[STRIP];            // 20.5 KB dense out-tile
    __shared__ unsigned wsum[4];
    __shared__ float b0s[CMID];
    __shared__ float w1s[CMID];
    __shared__ float b1s;

    int tid = threadIdx.x;
    int s   = blockIdx.x;
    int b   = s >> 10;
    int x   = (s >> 2) & 255;
    int ny0 = (s & 3) << 6;

    // --- zero out-tile (5 float4 per thread) ---
    float4* ot4 = (float4*)outt;
    float4 zf = {0.f, 0.f, 0.f, 0.f};
#pragma unroll
    for (int j = 0; j < 5; ++j) ot4[tid + j * 256] = zf;

    // --- mask table: entry e = kb[0,27)*8 + m[0,8); rows padded to 12 ---
    if (tid < 216) {
        int kb = tid >> 3;
        int m  = tid & 7;
        float acc[CMID];
#pragma unroll
        for (int c = 0; c < CMID; ++c) acc[c] = 0.0f;
#pragma unroll
        for (int dti = 0; dti < 3; ++dti) {
            if ((m >> dti) & 1) {
                const float* w = &W0[(kb * 3 + dti) * CMID];
#pragma unroll
                for (int c = 0; c < CMID; ++c) acc[c] += w[c];
            }
        }
#pragma unroll
        for (int c = 0; c < CMID; ++c) tab[tid * 12 + c] = acc[c];
    }
    if (tid < CMID) {
        b0s[tid] = b0[tid];
        w1s[tid] = W1[tid];
    }
    if (tid == 0) b1s = b1[0];

    // --- stage byte-grid neighborhood, pack bytes -> bits (R11-verified) ---
    for (int j = tid; j < 198 * 8; j += 256) {
        int cj  = j >> 3;           // column 0..197
        int zp  = j & 7;            // z-pair
        int r   = cj / 66;          // dxi
        int cyl = cj % 66;          // local ny + 1
        int nx  = x + r - 1;
        int cy  = ny0 + cyl - 1;
        bool valid = ((unsigned)nx < XD) && ((unsigned)cy < YD);
        int colidx = (b << 16) | ((nx & 255) << 8) | (cy & 255);
        ulonglong2 v = occ16[(colidx << 3) + zp];   // z = 2zp, 2zp+1
        unsigned m0 = pack8(v.x);
        unsigned m1 = pack8(v.y);
        unsigned short pk = (unsigned short)(m0 | (m1 << 8));
        ((unsigned short*)pcols)[cj * 8 + zp] = valid ? pk : (unsigned short)0;
    }
    __syncthreads();

    // --- compaction: u32 word tid of own 64 columns (base col idx 67) ---
    unsigned w = ((const unsigned*)pcols)[268 + tid];
    int cnt = __popc(w);

    unsigned pre = (unsigned)cnt;     // shfl inclusive wave-scan
#pragma unroll
    for (int off = 1; off < 64; off <<= 1) {
        unsigned v = (unsigned)__shfl_up((int)pre, off, 64);
        if ((tid & 63) >= off) pre += v;
    }
    int wv = tid >> 6;
    if ((tid & 63) == 63) wsum[wv] = pre;
    __syncthreads();
    unsigned base = 0;
#pragma unroll
    for (int k = 0; k < 4; ++k) base += (k < wv) ? wsum[k] : 0u;
    unsigned qlen = wsum[0] + wsum[1] + wsum[2] + wsum[3];
    if (qlen > QCAP) qlen = QCAP;     // never fires for this input (~350 max)
    unsigned pos  = base + pre - (unsigned)cnt;

    {
        int cl = tid >> 2;
        int zb = (tid & 3) << 2;
        unsigned ww = w;
        while (ww) {
            int bi = __ffs(ww) - 1;
            ww &= ww - 1;
            int zz = zb + (bi >> 3);
            int tt = bi & 7;
            if (pos < QCAP)
                queue[pos] = (unsigned short)((cl << 7) | (zz << 3) | tt);
            ++pos;
        }
    }
    __syncthreads();

    // --- conv over compacted entries (3 per-dxi partials for ILP) ---
    for (unsigned q = tid; q < qlen; q += 256) {
        int e  = queue[q];
        int cl = e >> 7;
        int z  = (e >> 3) & 15;
        int t  = e & 7;

        float4 p00 = zf, p01 = zf, p10 = zf, p11 = zf, p20 = zf, p21 = zf;
#pragma unroll
        for (int dxi = 0; dxi < 3; ++dxi) {
#pragma unroll
            for (int dyi = 0; dyi < 3; ++dyi) {
                ulonglong2 col = pcols[dxi * 66 + cl + dyi];
                int p3 = (dxi * 3 + dyi) * 3;
#pragma unroll
                for (int dzi = 0; dzi < 3; ++dzi) {
                    int nz = z + dzi - 1;                     // [-1, 16]
                    unsigned sh = ((unsigned)nz * 8u) & 63u;  // wrap-safe
                    unsigned r = (unsigned)(((nz & 8) ? (col.y >> sh)
                                                      : (col.x >> sh)) & 0xffull);
                    r = ((unsigned)nz < ZD) ? r : 0u;
                    unsigned m = ((r << 1) >> t) & 7u;  // bits t-1,t,t+1
                    if (m) {
                        const float4* row =
                            (const float4*)&tab[((p3 + dzi) * 8 + (int)m) * 12];
                        if (dxi == 0) { p00 += row[0]; p01 += row[1]; }
                        else if (dxi == 1) { p10 += row[0]; p11 += row[1]; }
                        else { p20 += row[0]; p21 += row[1]; }
                    }
                }
            }
        }
        // ordered combine: (p0 + p1) + p2  (regroup error ~1e-6, margin 47x)
        float4 h0 = (p00 + p10) + p20;
        float4 h1 = (p01 + p11) + p21;

        float hc[CMID] = {h0.x, h0.y, h0.z, h0.w, h1.x, h1.y, h1.z, h1.w};
        float o = 0.0f;
#pragma unroll
        for (int c = 0; c < CMID; ++c) {
            float v = 0.5f * hc[c] + b0s[c];   // grid value is exactly 0.5
            v = v > 0.0f ? v : 0.0f;           // relu
            o += v * w1s[c];
        }
        outt[cl * 80 + z * 5 + t] = o + b1s;
    }
    __syncthreads();

    // --- dense coalesced store of the whole strip (sole writer) ---
    const float4* src = (const float4*)outt;
    float4* dst = out4 + ((size_t)b * (VPB / 4)) + (size_t)(x * YD + ny0) * 20;
#pragma unroll
    for (int j = 0; j < 5; ++j) dst[tid + j * 256] = src[tid + j * 256];
}

extern "C" void kernel_launch(void* const* d_in, const int* in_sizes, int n_in,
                              void* d_out, int out_size, void* d_ws, size_t ws_size,
                              hipStream_t stream) {
    const float4* pts = (const float4*)d_in[0];
    const float* W0   = (const float*)d_in[1];
    const float* b0   = (const float*)d_in[2];
    const float* W1   = (const float*)d_in[3];
    const float* b1   = (const float*)d_in[4];
    unsigned char* occ8 = (unsigned char*)d_ws;   // 16 MiB byte grid

    zero_kernel<<<2048, 256, 0, stream>>>((uint4*)occ8);
    scatter_kernel<<<SCAT_BLOCKS, 256, 0, stream>>>(pts, occ8);
    conv_kernel<<<CONV_BLOCKS, 256, 0, stream>>>(
        (const ulonglong2*)occ8, W0, b0, W1, b1, (float4*)d_out);
}

// Round 15
// 45.665 us; speedup vs baseline: 1.5627x; 1.1584x over previous
//
#include <hip/hip_runtime.h>

// Problem constants (match reference)
#define XD 256
#define YD 256
#define ZD 16
#define TD 5
#define BD 2
#define NP 300000
#define CMID 8
#define VPB (XD * YD * ZD * TD)        // 5,242,880 voxels per batch
#define NVOX (BD * VPB)                // 10,485,760 total voxels
#define MAXPTS (BD * NP)               // 600,000

// Byte-per-voxel occupancy grid (scatter target; no atomics):
//   occ8[(colidx << 7) | (z << 3) | t], colidx = (b<<16)|(x<<8)|y
#define OCC8_BYTES (BD * XD * YD * ZD * 8)   // 16 MiB
#define OCC8_U128  (OCC8_BYTES / 16)         // 1,048,576
// Packed bitfield (pack kernel output; conv input): 16 B per column,
// bit (z*8+t) of the 128-bit column = occupancy of (z,t).
#define NCOL   (BD * XD * YD)                // 131,072 columns
#define PK_BYTES (NCOL * 16)                 // 2 MiB

#define SCAT_BLOCKS ((MAXPTS + 255) / 256)   // 2344
#define CONV_BLOCKS 2048                     // one (b, x, y-quarter) strip each
#define STRIP 5120                           // 64 cols * 80 outputs per strip
#define QCAP 512                             // strip occupancy ~283, max ~350

// ---------------------------------------------------------------------------
// Kernel 0: zero the 16 MiB byte grid.
// ---------------------------------------------------------------------------
__global__ __launch_bounds__(256) void zero_kernel(uint4* __restrict__ occ) {
    int i = blockIdx.x * 256 + threadIdx.x;
    uint4 z = {0u, 0u, 0u, 0u};
    for (int j = i; j < OCC8_U128; j += 2048 * 256) occ[j] = z;
}

// ---------------------------------------------------------------------------
// Kernel 1: scatter points -> occupancy bytes (plain stores, NO atomics).
// ---------------------------------------------------------------------------
__global__ __launch_bounds__(256) void scatter_kernel(
    const float4* __restrict__ pts, unsigned char* __restrict__ occ8) {
    int i = blockIdx.x * 256 + threadIdx.x;
    if (i >= MAXPTS) return;
    float4 p = pts[i];
    // Match JAX exactly: floor(p / quant) (fp32 division), then clip.
    int cx = min(max((int)floorf(p.x / 0.4f), 0), XD - 1);
    int cy = min(max((int)floorf(p.y / 0.4f), 0), YD - 1);
    int cz = min(max((int)floorf(p.z / 0.4f), 0), ZD - 1);
    int ct = min(max((int)floorf(p.w / 1.0f), 0), TD - 1);
    int b  = i / NP;
    unsigned a = (((unsigned)b << 23) | ((unsigned)cx << 15) |
                  ((unsigned)cy << 7) | ((unsigned)cz << 3) | (unsigned)ct);
    occ8[a] = 1;
}

// LSB-gather: u64 of 8 bytes (each 0 or 1) -> 8-bit mask (byte j -> bit j).
__device__ __forceinline__ unsigned pack8(unsigned long long v) {
    v |= v >> 7;
    v |= v >> 14;
    v |= v >> 28;
    return (unsigned)v & 0xffu;
}

// ---------------------------------------------------------------------------
// Kernel 2: pack byte grid -> 2 MiB bitfield (fully coalesced both sides).
// Thread j: column cj = j>>3, z-pair zp = j&7; 16 B in -> u16 out.
// ---------------------------------------------------------------------------
__global__ __launch_bounds__(256) void pack_kernel(
    const ulonglong2* __restrict__ occ16, unsigned short* __restrict__ pk) {
    int j = blockIdx.x * 256 + threadIdx.x;   // grid covers OCC8_U128 exactly
    ulonglong2 v = occ16[j];
    pk[j] = (unsigned short)(pack8(v.x) | (pack8(v.y) << 8));
}

// ---------------------------------------------------------------------------
// Kernel 3: strip conv. Block owns columns (b, x, ny0..ny0+63), sole writer
// of its 20 KB output strip.
//   1. stage 198 packed columns (3.2 KB, L2-resident 2 MB bitfield)
//   2. shfl-scan compaction into a balanced LDS queue
//   3. per entry: branchless mask27 prep (27 x 3-bit masks in 2 u64 regs +
//      27-bit fire mask), then ffs-iterate ONLY the ~4.3 firing taps
//      (ascending k == reference accumulation order); ReLU + 8->1 proj
//   4. dense coalesced float4 store of the strip from the LDS out-tile
// ---------------------------------------------------------------------------
__global__ __launch_bounds__(256) void conv_kernel(
    const ulonglong2* __restrict__ pk128,   // packed bitfield, 16 B/column
    const float* __restrict__ W0,   // (81, 1, 8)
    const float* __restrict__ b0,   // (8)
    const float* __restrict__ W1,   // (8, 1)
    const float* __restrict__ b1,   // (1)
    float4* __restrict__ out4) {
    __shared__ float tab[216 * 12];            // 10.4 KB mask table
    __shared__ unsigned long long clo[3 * 66]; // 1.6 KB (z 0..7 of each col)
    __shared__ unsigned long long chi[3 * 66]; // 1.6 KB (z 8..15)
    __shared__ unsigned short queue[QCAP];     // 1 KB
    __shared__ float outt[STRIP];              // 20.5 KB dense out-tile
    __shared__ unsigned wsum[4];
    __shared__ float b0s[CMID];
    __shared__ float w1s[CMID];
    __shared__ float b1sv;

    int tid = threadIdx.x;
    int s   = blockIdx.x;
    int b   = s >> 10;
    int x   = (s >> 2) & 255;
    int ny0 = (s & 3) << 6;

    // --- zero out-tile ---
    float4* ot4 = (float4*)outt;
    float4 zf = {0.f, 0.f, 0.f, 0.f};
#pragma unroll
    for (int j = 0; j < 5; ++j) ot4[tid + j * 256] = zf;

    // --- mask table: entry e = k[0,27)*8 + m[0,8); rows padded to 12 ---
    if (tid < 216) {
        int kb = tid >> 3;
        int m  = tid & 7;
        float acc[CMID];
#pragma unroll
        for (int c = 0; c < CMID; ++c) acc[c] = 0.0f;
#pragma unroll
        for (int dti = 0; dti < 3; ++dti) {
            if ((m >> dti) & 1) {
                const float* w = &W0[(kb * 3 + dti) * CMID];
#pragma unroll
                for (int c = 0; c < CMID; ++c) acc[c] += w[c];
            }
        }
#pragma unroll
        for (int c = 0; c < CMID; ++c) tab[tid * 12 + c] = acc[c];
    }
    if (tid < CMID) {
        b0s[tid] = b0[tid];
        w1s[tid] = W1[tid];
    }
    if (tid == 0) b1sv = b1[0];

    // --- stage 198 packed columns ---
    if (tid < 3 * 66) {
        int r   = tid / 66;         // dxi
        int cyl = tid % 66;         // local ny + 1
        int nx  = x + r - 1;
        int cy  = ny0 + cyl - 1;
        bool valid = ((unsigned)nx < XD) && ((unsigned)cy < YD);
        ulonglong2 v = pk128[(b << 16) | ((nx & 255) << 8) | (cy & 255)];
        clo[tid] = valid ? v.x : 0ull;
        chi[tid] = valid ? v.y : 0ull;
    }
    __syncthreads();

    // --- compaction: u32 word (tid&3) of own column (tid>>2), base 67 ---
    {
    }
    unsigned long long cw = (tid & 2) ? chi[67 + (tid >> 2)]
                                      : clo[67 + (tid >> 2)];
    unsigned w = (unsigned)((tid & 1) ? (cw >> 32) : cw);
    int cnt = __popc(w);

    unsigned pre = (unsigned)cnt;     // shfl inclusive wave-scan
#pragma unroll
    for (int off = 1; off < 64; off <<= 1) {
        unsigned v = (unsigned)__shfl_up((int)pre, off, 64);
        if ((tid & 63) >= off) pre += v;
    }
    int wv = tid >> 6;
    if ((tid & 63) == 63) wsum[wv] = pre;
    __syncthreads();
    unsigned base = 0;
#pragma unroll
    for (int k = 0; k < 4; ++k) base += (k < wv) ? wsum[k] : 0u;
    unsigned qlen = wsum[0] + wsum[1] + wsum[2] + wsum[3];
    if (qlen > QCAP) qlen = QCAP;     // never fires (~350 max observed)
    unsigned pos  = base + pre - (unsigned)cnt;

    {
        int cl = tid >> 2;
        int zb = (tid & 3) << 2;
        unsigned ww = w;
        while (ww) {
            int bi = __ffs(ww) - 1;
            ww &= ww - 1;
            int zz = zb + (bi >> 3);
            int tt = bi & 7;        // always < 5
            if (pos < QCAP)
                queue[pos] = (unsigned short)((cl << 7) | (zz << 3) | tt);
            ++pos;
        }
    }
    __syncthreads();

    // --- conv over compacted entries ---
    for (unsigned q = tid; q < qlen; q += 256) {
        int e  = queue[q];
        int cl = e >> 7;
        int z  = (e >> 3) & 15;
        int t  = e & 7;

        // Branchless prep: 27 masks -> fire-bitmask + packed 3-bit values.
        unsigned mask27 = 0u;
        unsigned long long mpA = 0ull, mpB = 0ull;
#pragma unroll
        for (int dxi = 0; dxi < 3; ++dxi) {
#pragma unroll
            for (int dyi = 0; dyi < 3; ++dyi) {
                int ci = dxi * 66 + cl + dyi;
                unsigned long long lo = clo[ci];
                unsigned long long hi = chi[ci];
                int k0 = (dxi * 3 + dyi) * 3;
#pragma unroll
                for (int dzi = 0; dzi < 3; ++dzi) {
                    int k = k0 + dzi;
                    int nz = z + dzi - 1;                     // [-1, 16]
                    unsigned sh = ((unsigned)nz * 8u) & 63u;  // wrap-safe
                    unsigned r = (unsigned)(((nz & 8) ? (hi >> sh)
                                                      : (lo >> sh)) & 0xffull);
                    r = ((unsigned)nz < ZD) ? r : 0u;
                    unsigned m = ((r << 1) >> t) & 7u;        // bits t-1..t+1
                    mask27 |= (m ? 1u : 0u) << k;
                    if (k < 21) mpA |= (unsigned long long)m << (3 * k);
                    else        mpB |= (unsigned long long)m << (3 * (k - 21));
                }
            }
        }

        // ffs loop over firing taps only (ascending k = reference order).
        float4 h0 = zf, h1 = zf;
        while (mask27) {
            int k = __ffs(mask27) - 1;
            mask27 &= mask27 - 1;
            unsigned long long mp = (k < 21) ? mpA : mpB;
            int kk = (k < 21) ? k : k - 21;
            unsigned m = (unsigned)(mp >> (3 * kk)) & 7u;
            const float4* row = (const float4*)&tab[(k * 8 + (int)m) * 12];
            h0 += row[0];
            h1 += row[1];
        }

        float hc[CMID] = {h0.x, h0.y, h0.z, h0.w, h1.x, h1.y, h1.z, h1.w};
        float o = 0.0f;
#pragma unroll
        for (int c = 0; c < CMID; ++c) {
            float v = 0.5f * hc[c] + b0s[c];   // grid value is exactly 0.5
            v = v > 0.0f ? v : 0.0f;           // relu
            o += v * w1s[c];
        }
        outt[cl * 80 + z * 5 + t] = o + b1sv;
    }
    __syncthreads();

    // --- dense coalesced store of the whole strip (sole writer) ---
    const float4* src = (const float4*)outt;
    float4* dst = out4 + ((size_t)b * (VPB / 4)) + (size_t)(x * YD + ny0) * 20;
#pragma unroll
    for (int j = 0; j < 5; ++j) dst[tid + j * 256] = src[tid + j * 256];
}

extern "C" void kernel_launch(void* const* d_in, const int* in_sizes, int n_in,
                              void* d_out, int out_size, void* d_ws, size_t ws_size,
                              hipStream_t stream) {
    const float4* pts = (const float4*)d_in[0];
    const float* W0   = (const float*)d_in[1];
    const float* b0   = (const float*)d_in[2];
    const float* W1   = (const float*)d_in[3];
    const float* b1   = (const float*)d_in[4];
    unsigned char* occ8 = (unsigned char*)d_ws;               // 16 MiB bytes
    unsigned short* pk  = (unsigned short*)((char*)d_ws + OCC8_BYTES); // 2 MiB

    zero_kernel<<<2048, 256, 0, stream>>>((uint4*)occ8);
    scatter_kernel<<<SCAT_BLOCKS, 256, 0, stream>>>(pts, occ8);
    pack_kernel<<<OCC8_U128 / 256, 256, 0, stream>>>(
        (const ulonglong2*)occ8, pk);
    conv_kernel<<<CONV_BLOCKS, 256, 0, stream>>>(
        (const ulonglong2*)pk, W0, b0, W1, b1, (float4*)d_out);
}

// Round 16
// 42.880 us; speedup vs baseline: 1.6642x; 1.0650x over previous
//
#include <hip/hip_runtime.h>

// Problem constants (match reference)
#define XD 256
#define YD 256
#define ZD 16
#define TD 5
#define BD 2
#define NP 300000
#define CMID 8
#define VPB (XD * YD * ZD * TD)        // 5,242,880 voxels per batch
#define NVOX (BD * VPB)                // 10,485,760 total voxels
#define MAXPTS (BD * NP)               // 600,000

// Byte-per-voxel occupancy grid (scatter target; no atomics):
//   occ8[(colidx << 7) | (z << 3) | t], colidx = (b<<16)|(x<<8)|y
#define OCC8_BYTES (BD * XD * YD * ZD * 8)   // 16 MiB
#define OCC8_U128  (OCC8_BYTES / 16)         // 1,048,576
// Packed bitfield (pack kernel output; conv input): 16 B per column,
// bit (z*8+t) = occupancy of (z,t).
#define NCOL   (BD * XD * YD)                // 131,072 columns

#define SCAT_BLOCKS ((MAXPTS + 255) / 256)   // 2344
#define CONV_BLOCKS 4096               // one (b, x, y-eighth) 32-col strip
#define CTHR 128                       // conv block threads
#define QCAP 512                       // 32-col strip occupancy ~142, max ~220

// ---------------------------------------------------------------------------
// Kernel 0: zero the 16 MiB byte grid.
// ---------------------------------------------------------------------------
__global__ __launch_bounds__(256) void zero_kernel(uint4* __restrict__ occ) {
    int i = blockIdx.x * 256 + threadIdx.x;
    uint4 z = {0u, 0u, 0u, 0u};
    for (int j = i; j < OCC8_U128; j += 2048 * 256) occ[j] = z;
}

// ---------------------------------------------------------------------------
// Kernel 1: scatter points -> occupancy bytes (plain stores, NO atomics).
// ---------------------------------------------------------------------------
__global__ __launch_bounds__(256) void scatter_kernel(
    const float4* __restrict__ pts, unsigned char* __restrict__ occ8) {
    int i = blockIdx.x * 256 + threadIdx.x;
    if (i >= MAXPTS) return;
    float4 p = pts[i];
    // Match JAX exactly: floor(p / quant) (fp32 division), then clip.
    int cx = min(max((int)floorf(p.x / 0.4f), 0), XD - 1);
    int cy = min(max((int)floorf(p.y / 0.4f), 0), YD - 1);
    int cz = min(max((int)floorf(p.z / 0.4f), 0), ZD - 1);
    int ct = min(max((int)floorf(p.w / 1.0f), 0), TD - 1);
    int b  = i / NP;
    unsigned a = (((unsigned)b << 23) | ((unsigned)cx << 15) |
                  ((unsigned)cy << 7) | ((unsigned)cz << 3) | (unsigned)ct);
    occ8[a] = 1;
}

// LSB-gather: u64 of 8 bytes (each 0 or 1) -> 8-bit mask (byte j -> bit j).
__device__ __forceinline__ unsigned pack8(unsigned long long v) {
    v |= v >> 7;
    v |= v >> 14;
    v |= v >> 28;
    return (unsigned)v & 0xffu;
}

// ---------------------------------------------------------------------------
// Kernel 2: pack byte grid -> 2 MiB bitfield (fully coalesced both sides).
// ---------------------------------------------------------------------------
__global__ __launch_bounds__(256) void pack_kernel(
    const ulonglong2* __restrict__ occ16, unsigned short* __restrict__ pk) {
    int j = blockIdx.x * 256 + threadIdx.x;   // grid covers OCC8_U128 exactly
    ulonglong2 v = occ16[j];
    pk[j] = (unsigned short)(pack8(v.x) | (pack8(v.y) << 8));
}

// ---------------------------------------------------------------------------
// Kernel 3: strip conv. Block (128 thr) owns columns (b, x, ny0..ny0+31),
// sole writer of its 10 KB output strip.
//   1. stage 3x34 packed columns (1.6 KB) + raw W0 rows (81x12f, 3.9 KB)
//   2. shfl-scan compaction into a balanced LDS queue
//   3. per entry: per-column byte-window funnel shift -> 9-bit mask chunk;
//      concatenated chunks form an 81-bit FIRE MASK over W0 rows; ffs-iterate
//      only firing rows (~5.6), ascending = exact reference accumulation
//      order. ReLU + 8->1 proj -> LDS out-tile.
//   4. dense coalesced float4 store of the strip (5 per thread, exact)
// ---------------------------------------------------------------------------
__global__ __launch_bounds__(CTHR) void conv_kernel(
    const ulonglong2* __restrict__ pk128,   // packed bitfield, 16 B/column
    const float* __restrict__ W0,   // (81, 1, 8)
    const float* __restrict__ b0,   // (8)
    const float* __restrict__ W1,   // (8, 1)
    const float* __restrict__ b1,   // (1)
    float4* __restrict__ out4) {
    __shared__ float w0s[81 * 12];             // 3.9 KB raw W0 rows (pad 12)
    __shared__ unsigned long long clo[3 * 34]; // z 0..7 of each column
    __shared__ unsigned long long chi[3 * 34]; // z 8..15
    __shared__ unsigned short queue[QCAP];     // 1 KB
    __shared__ float outt[32 * 80];            // 10 KB dense out-tile
    __shared__ unsigned wsum[2];
    __shared__ float b0s[CMID];
    __shared__ float w1s[CMID];
    __shared__ float b1sv;

    int tid = threadIdx.x;
    int s   = blockIdx.x;
    int b   = s >> 11;
    int x   = (s >> 3) & 255;
    int ny0 = (s & 7) << 5;

    // --- zero out-tile (5 float4 per thread, exact) ---
    float4* ot4 = (float4*)outt;
    float4 zf = {0.f, 0.f, 0.f, 0.f};
#pragma unroll
    for (int j = 0; j < 5; ++j) ot4[tid + j * CTHR] = zf;

    // --- stage W0 rows (81 x 8 -> pad 12) ---
    if (tid < 81) {
#pragma unroll
        for (int c = 0; c < CMID; ++c) w0s[tid * 12 + c] = W0[tid * CMID + c];
    }
    if (tid < CMID) {
        b0s[tid] = b0[tid];
        w1s[tid] = W1[tid];
    }
    if (tid == 0) b1sv = b1[0];

    // --- stage 3x34 packed columns ---
    if (tid < 3 * 34) {
        int r   = tid / 34;         // dxi
        int cyl = tid % 34;         // local ny + 1
        int nx  = x + r - 1;
        int cy  = ny0 + cyl - 1;
        bool valid = ((unsigned)nx < XD) && ((unsigned)cy < YD);
        ulonglong2 v = pk128[(b << 16) | ((nx & 255) << 8) | (cy & 255)];
        clo[tid] = valid ? v.x : 0ull;
        chi[tid] = valid ? v.y : 0ull;
    }
    __syncthreads();

    // --- compaction: u32 word (tid&3) of own column (tid>>2), base 35 ---
    unsigned long long cw = (tid & 2) ? chi[35 + (tid >> 2)]
                                      : clo[35 + (tid >> 2)];
    unsigned w = (unsigned)((tid & 1) ? (cw >> 32) : cw);
    int cnt = __popc(w);

    unsigned pre = (unsigned)cnt;     // shfl inclusive wave-scan (2 waves)
#pragma unroll
    for (int off = 1; off < 64; off <<= 1) {
        unsigned v = (unsigned)__shfl_up((int)pre, off, 64);
        if ((tid & 63) >= off) pre += v;
    }
    int wv = tid >> 6;
    if ((tid & 63) == 63) wsum[wv] = pre;
    __syncthreads();
    unsigned qlen = wsum[0] + wsum[1];
    if (qlen > QCAP) qlen = QCAP;     // never fires (~220 max)
    unsigned pos = ((wv == 1) ? wsum[0] : 0u) + pre - (unsigned)cnt;

    {
        int cl = tid >> 2;
        int zb = (tid & 3) << 2;
        unsigned ww = w;
        while (ww) {
            int bi = __ffs(ww) - 1;
            ww &= ww - 1;
            int zz = zb + (bi >> 3);
            int tt = bi & 7;        // always < 5
            if (pos < QCAP)
                queue[pos] = (unsigned short)((cl << 7) | (zz << 3) | tt);
            ++pos;
        }
    }
    __syncthreads();

    // --- conv over compacted entries ---
    for (unsigned q = tid; q < qlen; q += CTHR) {
        int e  = queue[q];
        int cl = e >> 7;
        int z  = (e >> 3) & 15;
        int t  = e & 7;

        // Build the 81-bit fire mask over W0 rows: per column, one funnel-
        // shifted 3-byte window around z, then 9 consecutive mask bits.
        unsigned long long mpA = 0ull;  // rows 0..62  (columns 0..6)
        unsigned mpB = 0u;              // rows 63..80 (columns 7..8)
        int sft = (z - 1) * 8;
#pragma unroll
        for (int dxi = 0; dxi < 3; ++dxi) {
#pragma unroll
            for (int dyi = 0; dyi < 3; ++dyi) {
                int ci = dxi * 34 + cl + dyi;
                unsigned long long lo = clo[ci];
                unsigned long long hi = chi[ci];
                unsigned long long wv64 =
                    (z == 0) ? (lo << 8)
                  : (z <= 8) ? ((lo >> sft) | ((hi << 1) << (63 - sft)))
                             : (hi >> (sft - 64));
                unsigned qw = (((unsigned)wv64 & 0xffffffu) << 1) >> t;
                unsigned nine = (qw & 7u) | (((qw >> 8) & 7u) << 3) |
                                (((qw >> 16) & 7u) << 6);
                int c9 = dxi * 3 + dyi;
                if (c9 < 7) mpA |= (unsigned long long)nine << (9 * c9);
                else if (c9 == 7) mpB |= nine;
                else mpB |= nine << 9;
            }
        }

        // ffs over firing W0 rows; ascending = reference accumulation order.
        float4 h0 = zf, h1 = zf;
        while (mpA) {
            int j = __ffsll((unsigned long long)mpA) - 1;
            mpA &= mpA - 1;
            const float4* row = (const float4*)&w0s[j * 12];
            h0 += row[0];
            h1 += row[1];
        }
        while (mpB) {
            int j = __ffs(mpB) - 1;
            mpB &= mpB - 1;
            const float4* row = (const float4*)&w0s[(63 + j) * 12];
            h0 += row[0];
            h1 += row[1];
        }

        float hc[CMID] = {h0.x, h0.y, h0.z, h0.w, h1.x, h1.y, h1.z, h1.w};
        float o = 0.0f;
#pragma unroll
        for (int c = 0; c < CMID; ++c) {
            float v = 0.5f * hc[c] + b0s[c];   // grid value is exactly 0.5
            v = v > 0.0f ? v : 0.0f;           // relu
            o += v * w1s[c];
        }
        outt[cl * 80 + z * 5 + t] = o + b1sv;
    }
    __syncthreads();

    // --- dense coalesced store of the whole strip (sole writer) ---
    const float4* src = (const float4*)outt;
    float4* dst = out4 + ((size_t)b * (VPB / 4)) + (size_t)(x * YD + ny0) * 20;
#pragma unroll
    for (int j = 0; j < 5; ++j) dst[tid + j * CTHR] = src[tid + j * CTHR];
}

extern "C" void kernel_launch(void* const* d_in, const int* in_sizes, int n_in,
                              void* d_out, int out_size, void* d_ws, size_t ws_size,
                              hipStream_t stream) {
    const float4* pts = (const float4*)d_in[0];
    const float* W0   = (const float*)d_in[1];
    const float* b0   = (const float*)d_in[2];
    const float* W1   = (const float*)d_in[3];
    const float* b1   = (const float*)d_in[4];
    unsigned char* occ8 = (unsigned char*)d_ws;               // 16 MiB bytes
    unsigned short* pk  = (unsigned short*)((char*)d_ws + OCC8_BYTES); // 2 MiB

    zero_kernel<<<2048, 256, 0, stream>>>((uint4*)occ8);
    scatter_kernel<<<SCAT_BLOCKS, 256, 0, stream>>>(pts, occ8);
    pack_kernel<<<OCC8_U128 / 256, 256, 0, stream>>>(
        (const ulonglong2*)occ8, pk);
    conv_kernel<<<CONV_BLOCKS, 128, 0, stream>>>(
        (const ulonglong2*)pk, W0, b0, W1, b1, (float4*)d_out);
}